// Round 11
// baseline (582.562 us; speedup 1.0000x reference)
//
#include <hip/hip_runtime.h>
#include <hip/hip_cooperative_groups.h>

namespace cg = cooperative_groups;

#define F 128

typedef __bf16 bf16x8 __attribute__((ext_vector_type(8)));
typedef float f32x4 __attribute__((ext_vector_type(4)));

// ---------------- fused prep ----------------
// blocks 0..63: W1 swizzle->bf16 fragments; block 64: w2l/cconst + zero histg;
// blocks 65..65+bG-1: gstart + gacc zero; rest: deg = 1 init.
__global__ __launch_bounds__(256) void k_prep(const float* __restrict__ W1, const float* __restrict__ W2,
                                              const float* __restrict__ Wlin, const float* __restrict__ b2,
                                              const float* __restrict__ blin, const int* __restrict__ batch,
                                              __bf16* __restrict__ Bswz, float* __restrict__ w2l,
                                              float* __restrict__ cconst, int* __restrict__ gstart,
                                              int* __restrict__ histg, float* __restrict__ deg,
                                              float* __restrict__ gacc, int N, int G, int bG) {
    int bid = blockIdx.x;
    int tid = threadIdx.x;
    if (bid < 64) {
        // Bswz[((t*8+c)*64+lane)*8+j] = W1[t*32+(lane>>4)*8+j][c*16+(lane&15)]
        int o = bid * 256 + tid;
        int j = o & 7, lane = (o >> 3) & 63, tc = o >> 9;
        int t = tc >> 3, c = tc & 7;
        int k = t * 32 + (lane >> 4) * 8 + j;
        int n = c * 16 + (lane & 15);
        Bswz[o] = (__bf16)W1[k * F + n];
    } else if (bid == 64) {
        __shared__ float sh[F];
        if (tid < F) {
            float s = 0.0f;
            for (int j = 0; j < F; j += 4) {
                float4 w = *(const float4*)&W2[tid * F + j];
                float4 l = *(const float4*)&Wlin[j];
                s += w.x * l.x + w.y * l.y + w.z * l.z + w.w * l.w;
            }
            w2l[tid] = s;
            sh[tid] = b2[tid] * Wlin[tid];
        } else if (tid < F + 64) {
            histg[tid - F] = 0;
        }
        __syncthreads();
        if (tid == 0) {
            float c = blin[0];
            for (int j = 0; j < F; ++j) c += sh[j];
            *cconst = c;
        }
    } else if (bid < 65 + bG) {
        int g = (bid - 65) * 256 + tid;
        if (g < G) {
            int lo = 0, hi = N;
            while (lo < hi) { int mid = (lo + hi) >> 1; if (batch[mid] < g) lo = mid + 1; else hi = mid; }
            gstart[g] = lo;
            gacc[g] = 0.0f;
            if (g == 0) gstart[G] = N;
        }
    } else {
        int i = (bid - 65 - bG) * 256 + tid;
        if (i < N) deg[i] = 1.0f;           // self-loop
    }
}

// ---------------- cooperative CSR build: count -> scan -> offsets -> fill+perm ----------------
// Phase bodies identical to the previous k_count/k_scan1/k_scan3/k_fill, grid-strided.
__global__ __launch_bounds__(256, 4) void k_graph(const int* __restrict__ src, const int* __restrict__ dst,
                                                  float* __restrict__ deg, int* __restrict__ pref,
                                                  int* __restrict__ bsum, float* __restrict__ dis,
                                                  int* __restrict__ histg, int* __restrict__ cursor,
                                                  int* __restrict__ srcs, int* __restrict__ bcur,
                                                  int* __restrict__ perm,
                                                  int N, int E, int nbN, int nbS) {
    cg::grid_group grid = cg::this_grid();
    int tid = threadIdx.x;
    int nthreads = gridDim.x * 256;
    __shared__ int lh[64];
    __shared__ int wtot[4];
    __shared__ int ws4[4];
    __shared__ int lcnt[64], lbase[64];

    // ---- phase A: degree count (4 edges/thread, int4) ----
    for (int i = blockIdx.x * 256 + tid; i < (E >> 2); i += nthreads) {
        int4 d = *(const int4*)(dst + i * 4);
        unsafeAtomicAdd(&deg[d.x], 1.0f);
        unsafeAtomicAdd(&deg[d.y], 1.0f);
        unsafeAtomicAdd(&deg[d.z], 1.0f);
        unsafeAtomicAdd(&deg[d.w], 1.0f);
    }
    if (blockIdx.x == 0 && tid < (E & 3))
        unsafeAtomicAdd(&deg[dst[(E & ~3) + tid]], 1.0f);
    grid.sync();

    // ---- phase B: per-1024-chunk exclusive scan of indeg; dis = rsqrt(deg); histogram ----
    for (int vb = blockIdx.x; vb < nbS; vb += gridDim.x) {
        if (tid < 64) lh[tid] = 0;
        int base = vb * 1024 + tid * 4;
        int v[4]; int s = 0;
#pragma unroll
        for (int j = 0; j < 4; ++j) {
            int idx = base + j;
            float dv = (idx < N) ? deg[idx] : 1.0f;
            if (idx < N) dis[idx] = rsqrtf(dv);
            v[j] = (idx < N) ? ((int)dv - 1) : 0; s += v[j];
        }
        int lane = tid & 63, w = tid >> 6;
        int inc = s;
#pragma unroll
        for (int d = 1; d < 64; d <<= 1) { int o = __shfl_up(inc, d); if (lane >= d) inc += o; }
        if (lane == 63) wtot[w] = inc;
        __syncthreads();
#pragma unroll
        for (int j = 0; j < 4; ++j)
            if (base + j < N) atomicAdd(&lh[min(v[j], 63)], 1);
        int woff = 0;
#pragma unroll
        for (int i = 0; i < 4; ++i) if (i < w) woff += wtot[i];
        int run = woff + inc - s;
#pragma unroll
        for (int j = 0; j < 4; ++j) { int idx = base + j; if (idx < N) pref[idx] = run; run += v[j]; }
        if (tid == 255) bsum[vb] = woff + inc;
        __syncthreads();
        if (tid < 64 && lh[tid] > 0) atomicAdd(&histg[tid], lh[tid]);
    }
    grid.sync();

    // ---- phase C: add block offsets; block 0 scans histogram -> bucket cursors ----
    for (int vb = blockIdx.x; vb < nbN; vb += gridDim.x) {
        int chunk = vb >> 2;
        int partial = 0;
        for (int i = tid; i < chunk; i += 256) partial += bsum[i];
        int lane = tid & 63, w = tid >> 6;
#pragma unroll
        for (int d = 1; d < 64; d <<= 1) partial += __shfl_xor(partial, d);
        if (lane == 0) ws4[w] = partial;
        __syncthreads();
        int off = ws4[0] + ws4[1] + ws4[2] + ws4[3];
        int i2 = vb * 256 + tid;
        if (i2 < N) {
            int vv = pref[i2] + off;
            pref[i2] = vv;
            cursor[i2] = vv;
        }
        if (i2 == 0) pref[N] = E;
        __syncthreads();
    }
    if (blockIdx.x == 0 && tid < 64) {
        int h = histg[tid];
        int inc2 = h;
#pragma unroll
        for (int d = 1; d < 64; d <<= 1) { int o = __shfl_up(inc2, d); if (tid >= d) inc2 += o; }
        bcur[tid] = inc2 - h;
    }
    grid.sync();

    // ---- phase D: degree-sorted perm scatter, then CSR edge fill ----
    for (int vb = blockIdx.x; vb < nbN; vb += gridDim.x) {
        if (tid < 64) lcnt[tid] = 0;
        __syncthreads();
        int n = vb * 256 + tid;
        int b = 0, r = 0;
        if (n < N) {
            b = min((int)deg[n] - 1, 63);
            r = atomicAdd(&lcnt[b], 1);
        }
        __syncthreads();
        if (tid < 64 && lcnt[tid] > 0) lbase[tid] = atomicAdd(&bcur[tid], lcnt[tid]);
        __syncthreads();
        if (n < N) perm[lbase[b] + r] = n;
        __syncthreads();
    }
    for (int i = blockIdx.x * 256 + tid; i < (E >> 2); i += nthreads) {
        int4 s4 = *(const int4*)(src + i * 4);
        int4 d4 = *(const int4*)(dst + i * 4);
        srcs[atomicAdd(&cursor[d4.x], 1)] = s4.x;
        srcs[atomicAdd(&cursor[d4.y], 1)] = s4.y;
        srcs[atomicAdd(&cursor[d4.z], 1)] = s4.z;
        srcs[atomicAdd(&cursor[d4.w], 1)] = s4.w;
    }
    if (blockIdx.x == 0 && tid < (E & 3)) {
        int e = (E & ~3) + tid;
        srcs[atomicAdd(&cursor[dst[e]], 1)] = src[e];
    }
}

// ---------------- MFMA GEMM: Yb[n] = bf16( dis[n] * (X @ W)[n] ) ----------------
// R8 form: 1-deep A prefetch, batched coalesced B loads (L2-resident), t-loop not unrolled.
__global__ __launch_bounds__(256) void k_gemm_mfma(const float* __restrict__ X,
                                                   const __bf16* __restrict__ Bswz,
                                                   const float* __restrict__ dis,
                                                   __bf16* __restrict__ Yb, int N) {
    int lane = threadIdx.x & 63, wave = threadIdx.x >> 6;
    int quad = lane >> 4, m = lane & 15;
    int r0 = blockIdx.x * 128 + wave * 32;

    f32x4 acc[2][8];
#pragma unroll
    for (int rt = 0; rt < 2; ++rt)
#pragma unroll
        for (int c = 0; c < 8; ++c) acc[rt][c] = (f32x4)0.0f;

    int ra = r0 + m;      if (ra >= N) ra = N - 1;
    int rb = r0 + 16 + m; if (rb >= N) rb = N - 1;
    const float* pxa = &X[(size_t)ra * F + quad * 8];
    const float* pxb = &X[(size_t)rb * F + quad * 8];

    float4 a0 = *(const float4*)pxa, a1 = *(const float4*)(pxa + 4);
    float4 a2 = *(const float4*)pxb, a3 = *(const float4*)(pxb + 4);

#pragma unroll 1
    for (int t = 0; t < 4; ++t) {
        const __bf16* bp = Bswz + (size_t)t * 4096 + lane * 8;
        bf16x8 B[8];
#pragma unroll
        for (int c = 0; c < 8; ++c) B[c] = *(const bf16x8*)(bp + c * 512);

        float fa[8] = {a0.x, a0.y, a0.z, a0.w, a1.x, a1.y, a1.z, a1.w};
        float fb[8] = {a2.x, a2.y, a2.z, a2.w, a3.x, a3.y, a3.z, a3.w};
        bf16x8 ah0, al0, ah1, al1;
#pragma unroll
        for (int j = 0; j < 8; ++j) {
            __bf16 h0 = (__bf16)fa[j]; ah0[j] = h0; al0[j] = (__bf16)(fa[j] - (float)h0);
            __bf16 h1 = (__bf16)fb[j]; ah1[j] = h1; al1[j] = (__bf16)(fb[j] - (float)h1);
        }
        if (t < 3) {
            a0 = *(const float4*)(pxa + (t + 1) * 32);
            a1 = *(const float4*)(pxa + (t + 1) * 32 + 4);
            a2 = *(const float4*)(pxb + (t + 1) * 32);
            a3 = *(const float4*)(pxb + (t + 1) * 32 + 4);
        }
#pragma unroll
        for (int c = 0; c < 8; ++c) {
            acc[0][c] = __builtin_amdgcn_mfma_f32_16x16x32_bf16(ah0, B[c], acc[0][c], 0, 0, 0);
            acc[0][c] = __builtin_amdgcn_mfma_f32_16x16x32_bf16(al0, B[c], acc[0][c], 0, 0, 0);
            acc[1][c] = __builtin_amdgcn_mfma_f32_16x16x32_bf16(ah1, B[c], acc[1][c], 0, 0, 0);
            acc[1][c] = __builtin_amdgcn_mfma_f32_16x16x32_bf16(al1, B[c], acc[1][c], 0, 0, 0);
        }
    }

#pragma unroll
    for (int rt = 0; rt < 2; ++rt) {
        int rbase = r0 + rt * 16 + quad * 4;
#pragma unroll
        for (int r = 0; r < 4; ++r) {
            int row = rbase + r;
            if (row < N) {
                float dr = dis[row];
#pragma unroll
                for (int c = 0; c < 8; ++c)
                    Yb[(size_t)row * F + c * 16 + m] = (__bf16)(acc[rt][c][r] * dr);
            }
        }
    }
}

// ---------------- layer-1 aggregation + zt = dis*(relu(b1+dis*sum).w2l), degree-sorted ------
// R8 form: 8 lanes/node, 4-edge unroll (8 loads/lane in flight), degree-sorted perm.
__global__ __launch_bounds__(256) void k_agg_z(const __bf16* __restrict__ hWb, const float* __restrict__ dis,
                                               const int* __restrict__ rowptr, const int* __restrict__ srcs,
                                               const int* __restrict__ perm,
                                               const float* __restrict__ bias, const float* __restrict__ w2l,
                                               float* __restrict__ zt, int N) {
    int idx = blockIdx.x * 32 + (threadIdx.x >> 3);
    if (idx >= N) return;
    int node = perm[idx];
    int lane = threadIdx.x & 7;                   // 8 lanes/node, 16 elems/lane
    float di = dis[node];
    float s[16];
    {
        const __bf16* pr = &hWb[(size_t)node * F + lane * 16];
        bf16x8 v0 = *(const bf16x8*)pr;
        bf16x8 v1 = *(const bf16x8*)(pr + 8);
#pragma unroll
        for (int j = 0; j < 8; ++j) { s[j] = (float)v0[j]; s[8 + j] = (float)v1[j]; }
    }
    int e0 = rowptr[node], e1 = rowptr[node + 1];
    int e = e0;
    for (; e + 4 <= e1; e += 4) {
        int i0 = srcs[e], i1 = srcs[e + 1], i2 = srcs[e + 2], i3 = srcs[e + 3];
        const __bf16* p0 = &hWb[(size_t)i0 * F + lane * 16];
        const __bf16* p1 = &hWb[(size_t)i1 * F + lane * 16];
        const __bf16* p2 = &hWb[(size_t)i2 * F + lane * 16];
        const __bf16* p3 = &hWb[(size_t)i3 * F + lane * 16];
        bf16x8 a0 = *(const bf16x8*)p0, b0 = *(const bf16x8*)(p0 + 8);
        bf16x8 a1 = *(const bf16x8*)p1, b1 = *(const bf16x8*)(p1 + 8);
        bf16x8 a2 = *(const bf16x8*)p2, b2 = *(const bf16x8*)(p2 + 8);
        bf16x8 a3 = *(const bf16x8*)p3, b3 = *(const bf16x8*)(p3 + 8);
#pragma unroll
        for (int j = 0; j < 8; ++j) {
            s[j]     += (float)a0[j] + (float)a1[j] + (float)a2[j] + (float)a3[j];
            s[8 + j] += (float)b0[j] + (float)b1[j] + (float)b2[j] + (float)b3[j];
        }
    }
    for (; e < e1; ++e) {
        const __bf16* pr = &hWb[(size_t)srcs[e] * F + lane * 16];
        bf16x8 v0 = *(const bf16x8*)pr;
        bf16x8 v1 = *(const bf16x8*)(pr + 8);
#pragma unroll
        for (int j = 0; j < 8; ++j) { s[j] += (float)v0[j]; s[8 + j] += (float)v1[j]; }
    }
    float p = 0.0f;
#pragma unroll
    for (int q = 0; q < 4; ++q) {
        float4 bb = *(const float4*)&bias[lane * 16 + q * 4];
        float4 ww = *(const float4*)&w2l[lane * 16 + q * 4];
        p += fmaxf(fmaf(di, s[q * 4 + 0], bb.x), 0.0f) * ww.x;
        p += fmaxf(fmaf(di, s[q * 4 + 1], bb.y), 0.0f) * ww.y;
        p += fmaxf(fmaf(di, s[q * 4 + 2], bb.z), 0.0f) * ww.z;
        p += fmaxf(fmaf(di, s[q * 4 + 3], bb.w), 0.0f) * ww.w;
    }
#pragma unroll
    for (int d = 1; d < 8; d <<= 1) p += __shfl_xor(p, d);
    if (lane == 0) zt[node] = di * p;
}

// ---------------- layer-2 aggregation + pool: degree-sorted thread-per-node + atomics ------
__global__ __launch_bounds__(256) void k_pool(const float* __restrict__ zt, const float* __restrict__ dis,
                                              const int* __restrict__ rowptr, const int* __restrict__ srcs,
                                              const int* __restrict__ perm, const int* __restrict__ batch,
                                              float* __restrict__ gacc, int N) {
    int idx = blockIdx.x * 256 + threadIdx.x;
    if (idx >= N) return;
    int n = perm[idx];                    // wave-uniform degree -> no divergence waste
    float s = zt[n];
    int e0 = rowptr[n], e1 = rowptr[n + 1];
    int e = e0;
    for (; e + 4 <= e1; e += 4) {
        s += zt[srcs[e]] + zt[srcs[e + 1]] + zt[srcs[e + 2]] + zt[srcs[e + 3]];
    }
    for (; e < e1; ++e) s += zt[srcs[e]];
    unsafeAtomicAdd(&gacc[batch[n]], dis[n] * s);
}

__global__ __launch_bounds__(256) void k_final(const float* __restrict__ gacc, const int* __restrict__ gstart,
                                               const float* __restrict__ cconst, const float* __restrict__ blin,
                                               float* __restrict__ out, int G) {
    int g = blockIdx.x * 256 + threadIdx.x;
    if (g < G) {
        int c = gstart[g + 1] - gstart[g];
        out[g] = (c > 0) ? (gacc[g] / (float)c + cconst[0]) : blin[0];
    }
}

// ---------------- launch ----------------

extern "C" void kernel_launch(void* const* d_in, const int* in_sizes, int n_in,
                              void* d_out, int out_size, void* d_ws, size_t ws_size,
                              hipStream_t stream) {
    const float* x    = (const float*)d_in[0];
    const int*   ei   = (const int*)d_in[1];
    const int*   batch= (const int*)d_in[2];
    const float* W1   = (const float*)d_in[3];
    const float* b1   = (const float*)d_in[4];
    const float* W2   = (const float*)d_in[5];
    const float* b2   = (const float*)d_in[6];
    const float* Wlin = (const float*)d_in[7];
    const float* blin = (const float*)d_in[8];
    float* out = (float*)d_out;

    const int N = in_sizes[2];          // 100000
    const int E = in_sizes[1] / 2;      // 600000
    const int G = out_size;             // 512
    const int* src = ei;
    const int* dst = ei + E;

    char* p = (char*)d_ws;
    auto take = [&](size_t bytes) { char* q = p; p += (bytes + 255) & ~(size_t)255; return q; };
    __bf16* hWb    = (__bf16*)take((size_t)N * F * 2);  // bf16( dis * (x @ W1) )
    float*  ztbuf  = (float*)take((size_t)N * 4);
    float*  deg    = (float*)take((size_t)N * 4);
    float*  dis    = (float*)take((size_t)N * 4);
    int*    rowptr = (int*)  take((size_t)(N + 1) * 4);
    int*    cursor = (int*)  take((size_t)N * 4);
    int*    srcs   = (int*)  take((size_t)E * 4);
    int*    perm   = (int*)  take((size_t)N * 4);
    int*    bsum   = (int*)  take(4096);
    int*    histg  = (int*)  take(64 * 4);
    int*    bcur   = (int*)  take(64 * 4);
    int*    gstart = (int*)  take((size_t)(G + 1) * 4);
    float*  gacc   = (float*)take((size_t)G * 4);
    float*  w2l    = (float*)take((size_t)F * 4);
    float*  cconst = (float*)take(256);
    __bf16* Bswz   = (__bf16*)take((size_t)F * F * 2);

    const int nbN  = (N + 255) / 256;
    const int nbS  = (N + 1023) / 1024;
    const int bG   = (G + 255) / 256;

    k_prep<<<65 + bG + nbN, 256, 0, stream>>>(W1, W2, Wlin, b2, blin, batch,
                                              Bswz, w2l, cconst, gstart, histg, deg, gacc, N, G, bG);

    {
        const int* srcp = src; const int* dstp = dst;
        int Nv = N, Ev = E, nbNv = nbN, nbSv = nbS;
        void* kargs[] = { (void*)&srcp, (void*)&dstp, (void*)&deg, (void*)&rowptr, (void*)&bsum,
                          (void*)&dis, (void*)&histg, (void*)&cursor, (void*)&srcs, (void*)&bcur,
                          (void*)&perm, (void*)&Nv, (void*)&Ev, (void*)&nbNv, (void*)&nbSv };
        hipLaunchCooperativeKernel((void*)k_graph, dim3(1024), dim3(256), kargs, 0, stream);
    }

    k_gemm_mfma<<<(N + 127) / 128, 256, 0, stream>>>(x, Bswz, dis, hWb, N);
    k_agg_z<<<(N + 31) / 32, 256, 0, stream>>>(hWb, dis, rowptr, srcs, perm, b1, w2l, ztbuf, N);
    k_pool<<<nbN, 256, 0, stream>>>(ztbuf, dis, rowptr, srcs, perm, batch, gacc, N);
    k_final<<<bG, 256, 0, stream>>>(gacc, gstart, cconst, blin, out, G);
}

// Round 12
// 292.592 us; speedup vs baseline: 1.9910x; 1.9910x over previous
//
#include <hip/hip_runtime.h>

#define F 128

typedef __bf16 bf16x8 __attribute__((ext_vector_type(8)));
typedef float f32x4 __attribute__((ext_vector_type(4)));

// ---------------- fused prep ----------------
// blocks 0..63: W1 swizzle->bf16 fragments; block 64: w2l/cconst + zero histg;
// blocks 65..65+bG-1: gstart + gacc zero; rest: deg = 1 init.
__global__ __launch_bounds__(256) void k_prep(const float* __restrict__ W1, const float* __restrict__ W2,
                                              const float* __restrict__ Wlin, const float* __restrict__ b2,
                                              const float* __restrict__ blin, const int* __restrict__ batch,
                                              __bf16* __restrict__ Bswz, float* __restrict__ w2l,
                                              float* __restrict__ cconst, int* __restrict__ gstart,
                                              int* __restrict__ histg, float* __restrict__ deg,
                                              float* __restrict__ gacc, int N, int G, int bG) {
    int bid = blockIdx.x;
    int tid = threadIdx.x;
    if (bid < 64) {
        // Bswz[((t*8+c)*64+lane)*8+j] = W1[t*32+(lane>>4)*8+j][c*16+(lane&15)]
        int o = bid * 256 + tid;
        int j = o & 7, lane = (o >> 3) & 63, tc = o >> 9;
        int t = tc >> 3, c = tc & 7;
        int k = t * 32 + (lane >> 4) * 8 + j;
        int n = c * 16 + (lane & 15);
        Bswz[o] = (__bf16)W1[k * F + n];
    } else if (bid == 64) {
        __shared__ float sh[F];
        if (tid < F) {
            float s = 0.0f;
            for (int j = 0; j < F; j += 4) {
                float4 w = *(const float4*)&W2[tid * F + j];
                float4 l = *(const float4*)&Wlin[j];
                s += w.x * l.x + w.y * l.y + w.z * l.z + w.w * l.w;
            }
            w2l[tid] = s;
            sh[tid] = b2[tid] * Wlin[tid];
        } else if (tid < F + 64) {
            histg[tid - F] = 0;
        }
        __syncthreads();
        if (tid == 0) {
            float c = blin[0];
            for (int j = 0; j < F; ++j) c += sh[j];
            *cconst = c;
        }
    } else if (bid < 65 + bG) {
        int g = (bid - 65) * 256 + tid;
        if (g < G) {
            int lo = 0, hi = N;
            while (lo < hi) { int mid = (lo + hi) >> 1; if (batch[mid] < g) lo = mid + 1; else hi = mid; }
            gstart[g] = lo;
            gacc[g] = 0.0f;
            if (g == 0) gstart[G] = N;
        }
    } else {
        int i = (bid - 65 - bG) * 256 + tid;
        if (i < N) deg[i] = 1.0f;           // self-loop
    }
}

// degree count: 4 edges/thread via int4, random-address atomics
__global__ __launch_bounds__(256) void k_count(const int* __restrict__ dst, float* deg, int E) {
    int base = (blockIdx.x * 256 + threadIdx.x) * 4;
    if (base + 4 <= E) {
        int4 d = *(const int4*)(dst + base);
        unsafeAtomicAdd(&deg[d.x], 1.0f);
        unsafeAtomicAdd(&deg[d.y], 1.0f);
        unsafeAtomicAdd(&deg[d.z], 1.0f);
        unsafeAtomicAdd(&deg[d.w], 1.0f);
    } else {
        for (int i = base; i < E; ++i) unsafeAtomicAdd(&deg[dst[i]], 1.0f);
    }
}

// exclusive scan of indeg (=deg-1), 1024 elems/block; dis = rsqrt(deg); + degree histogram
__global__ __launch_bounds__(256) void k_scan1(const float* __restrict__ deg, int* __restrict__ pref,
                                               int* __restrict__ bsum, float* __restrict__ dis,
                                               int* __restrict__ histg, int N) {
    int t = threadIdx.x;
    __shared__ int lh[64];
    __shared__ int wtot[4];
    if (t < 64) lh[t] = 0;
    int base = blockIdx.x * 1024 + t * 4;
    int v[4]; int s = 0;
#pragma unroll
    for (int j = 0; j < 4; ++j) {
        int idx = base + j;
        float dv = (idx < N) ? deg[idx] : 1.0f;
        if (idx < N) dis[idx] = rsqrtf(dv);
        v[j] = (idx < N) ? ((int)dv - 1) : 0; s += v[j];
    }
    int lane = t & 63, w = t >> 6;
    int inc = s;
#pragma unroll
    for (int d = 1; d < 64; d <<= 1) { int o = __shfl_up(inc, d); if (lane >= d) inc += o; }
    if (lane == 63) wtot[w] = inc;
    __syncthreads();                          // covers lh init + wtot
#pragma unroll
    for (int j = 0; j < 4; ++j)
        if (base + j < N) atomicAdd(&lh[min(v[j], 63)], 1);
    int woff = 0;
#pragma unroll
    for (int i = 0; i < 4; ++i) if (i < w) woff += wtot[i];
    int run = woff + inc - s;
#pragma unroll
    for (int j = 0; j < 4; ++j) { int idx = base + j; if (idx < N) pref[idx] = run; run += v[j]; }
    if (t == 255) bsum[blockIdx.x] = woff + inc;
    __syncthreads();
    if (t < 64 && lh[t] > 0) atomicAdd(&histg[t], lh[t]);
}

// add block offsets (reduce bsum[0..chunk) in-block); block 0 also scans the 64-bin histogram
__global__ __launch_bounds__(256) void k_scan3(int* __restrict__ pref, const int* __restrict__ bsum,
                                               int* __restrict__ cursor, const int* __restrict__ histg,
                                               int* __restrict__ bcur, int N, int E) {
    int t = threadIdx.x;
    int chunk = blockIdx.x >> 2;
    int partial = 0;
    for (int i = t; i < chunk; i += 256) partial += bsum[i];
    int lane = t & 63, w = t >> 6;
#pragma unroll
    for (int d = 1; d < 64; d <<= 1) partial += __shfl_xor(partial, d);
    __shared__ int ws4[4];
    if (lane == 0) ws4[w] = partial;
    __syncthreads();
    int off = ws4[0] + ws4[1] + ws4[2] + ws4[3];
    int i = blockIdx.x * 256 + t;
    if (i < N) {
        int v = pref[i] + off;
        pref[i] = v;
        cursor[i] = v;
    }
    if (i == 0) pref[N] = E;
    if (blockIdx.x == 0 && t < 64) {          // exclusive scan of degree histogram -> bucket cursors
        int h = histg[t];
        int inc2 = h;
#pragma unroll
        for (int d = 1; d < 64; d <<= 1) { int o = __shfl_up(inc2, d); if (t >= d) inc2 += o; }
        bcur[t] = inc2 - h;
    }
}

// CSR fill (edge-parallel blocks, 4 edges/thread) + degree-sorted perm scatter (node blocks)
__global__ __launch_bounds__(256) void k_fill(const int* __restrict__ src, const int* __restrict__ dst,
                                              const float* __restrict__ deg, int* __restrict__ cursor,
                                              int* __restrict__ srcs, int* __restrict__ bcur,
                                              int* __restrict__ perm, int E, int N, int nbN) {
    int bid = blockIdx.x, tid = threadIdx.x;
    if (bid < nbN) {
        __shared__ int lcnt[64], lbase[64];
        if (tid < 64) lcnt[tid] = 0;
        __syncthreads();
        int n = bid * 256 + tid;
        int b = 0, r = 0;
        if (n < N) {
            b = min((int)deg[n] - 1, 63);
            r = atomicAdd(&lcnt[b], 1);
        }
        __syncthreads();
        if (tid < 64 && lcnt[tid] > 0) lbase[tid] = atomicAdd(&bcur[tid], lcnt[tid]);
        __syncthreads();
        if (n < N) perm[lbase[b] + r] = n;
    } else {
        int base = ((bid - nbN) * 256 + tid) * 4;
        if (base + 4 <= E) {
            int4 s4 = *(const int4*)(src + base);
            int4 d4 = *(const int4*)(dst + base);
            srcs[atomicAdd(&cursor[d4.x], 1)] = s4.x;
            srcs[atomicAdd(&cursor[d4.y], 1)] = s4.y;
            srcs[atomicAdd(&cursor[d4.z], 1)] = s4.z;
            srcs[atomicAdd(&cursor[d4.w], 1)] = s4.w;
        } else {
            for (int e = base; e < E; ++e) {
                srcs[atomicAdd(&cursor[dst[e]], 1)] = src[e];
            }
        }
    }
}

// ---------------- MFMA GEMM: Yb[n] = bf16( dis[n] * (X @ W)[n] ) ----------------
// R8 form: 1-deep A prefetch, batched coalesced B loads (L2-resident), t-loop not unrolled.
__global__ __launch_bounds__(256) void k_gemm_mfma(const float* __restrict__ X,
                                                   const __bf16* __restrict__ Bswz,
                                                   const float* __restrict__ dis,
                                                   __bf16* __restrict__ Yb, int N) {
    int lane = threadIdx.x & 63, wave = threadIdx.x >> 6;
    int quad = lane >> 4, m = lane & 15;
    int r0 = blockIdx.x * 128 + wave * 32;

    f32x4 acc[2][8];
#pragma unroll
    for (int rt = 0; rt < 2; ++rt)
#pragma unroll
        for (int c = 0; c < 8; ++c) acc[rt][c] = (f32x4)0.0f;

    int ra = r0 + m;      if (ra >= N) ra = N - 1;
    int rb = r0 + 16 + m; if (rb >= N) rb = N - 1;
    const float* pxa = &X[(size_t)ra * F + quad * 8];
    const float* pxb = &X[(size_t)rb * F + quad * 8];

    float4 a0 = *(const float4*)pxa, a1 = *(const float4*)(pxa + 4);
    float4 a2 = *(const float4*)pxb, a3 = *(const float4*)(pxb + 4);

#pragma unroll 1
    for (int t = 0; t < 4; ++t) {
        const __bf16* bp = Bswz + (size_t)t * 4096 + lane * 8;
        bf16x8 B[8];
#pragma unroll
        for (int c = 0; c < 8; ++c) B[c] = *(const bf16x8*)(bp + c * 512);

        float fa[8] = {a0.x, a0.y, a0.z, a0.w, a1.x, a1.y, a1.z, a1.w};
        float fb[8] = {a2.x, a2.y, a2.z, a2.w, a3.x, a3.y, a3.z, a3.w};
        bf16x8 ah0, al0, ah1, al1;
#pragma unroll
        for (int j = 0; j < 8; ++j) {
            __bf16 h0 = (__bf16)fa[j]; ah0[j] = h0; al0[j] = (__bf16)(fa[j] - (float)h0);
            __bf16 h1 = (__bf16)fb[j]; ah1[j] = h1; al1[j] = (__bf16)(fb[j] - (float)h1);
        }
        if (t < 3) {
            a0 = *(const float4*)(pxa + (t + 1) * 32);
            a1 = *(const float4*)(pxa + (t + 1) * 32 + 4);
            a2 = *(const float4*)(pxb + (t + 1) * 32);
            a3 = *(const float4*)(pxb + (t + 1) * 32 + 4);
        }
#pragma unroll
        for (int c = 0; c < 8; ++c) {
            acc[0][c] = __builtin_amdgcn_mfma_f32_16x16x32_bf16(ah0, B[c], acc[0][c], 0, 0, 0);
            acc[0][c] = __builtin_amdgcn_mfma_f32_16x16x32_bf16(al0, B[c], acc[0][c], 0, 0, 0);
            acc[1][c] = __builtin_amdgcn_mfma_f32_16x16x32_bf16(ah1, B[c], acc[1][c], 0, 0, 0);
            acc[1][c] = __builtin_amdgcn_mfma_f32_16x16x32_bf16(al1, B[c], acc[1][c], 0, 0, 0);
        }
    }

#pragma unroll
    for (int rt = 0; rt < 2; ++rt) {
        int rbase = r0 + rt * 16 + quad * 4;
#pragma unroll
        for (int r = 0; r < 4; ++r) {
            int row = rbase + r;
            if (row < N) {
                float dr = dis[row];
#pragma unroll
                for (int c = 0; c < 8; ++c)
                    Yb[(size_t)row * F + c * 16 + m] = (__bf16)(acc[rt][c][r] * dr);
            }
        }
    }
}

// ---------------- layer-1 aggregation + zt = dis*(relu(b1+dis*sum).w2l), degree-sorted ------
// R8 form: 8 lanes/node, 4-edge unroll (8 loads/lane in flight), degree-sorted perm.
__global__ __launch_bounds__(256) void k_agg_z(const __bf16* __restrict__ hWb, const float* __restrict__ dis,
                                               const int* __restrict__ rowptr, const int* __restrict__ srcs,
                                               const int* __restrict__ perm,
                                               const float* __restrict__ bias, const float* __restrict__ w2l,
                                               float* __restrict__ zt, int N) {
    int idx = blockIdx.x * 32 + (threadIdx.x >> 3);
    if (idx >= N) return;
    int node = perm[idx];
    int lane = threadIdx.x & 7;                   // 8 lanes/node, 16 elems/lane
    float di = dis[node];
    float s[16];
    {
        const __bf16* pr = &hWb[(size_t)node * F + lane * 16];
        bf16x8 v0 = *(const bf16x8*)pr;
        bf16x8 v1 = *(const bf16x8*)(pr + 8);
#pragma unroll
        for (int j = 0; j < 8; ++j) { s[j] = (float)v0[j]; s[8 + j] = (float)v1[j]; }
    }
    int e0 = rowptr[node], e1 = rowptr[node + 1];
    int e = e0;
    for (; e + 4 <= e1; e += 4) {
        int i0 = srcs[e], i1 = srcs[e + 1], i2 = srcs[e + 2], i3 = srcs[e + 3];
        const __bf16* p0 = &hWb[(size_t)i0 * F + lane * 16];
        const __bf16* p1 = &hWb[(size_t)i1 * F + lane * 16];
        const __bf16* p2 = &hWb[(size_t)i2 * F + lane * 16];
        const __bf16* p3 = &hWb[(size_t)i3 * F + lane * 16];
        bf16x8 a0 = *(const bf16x8*)p0, b0 = *(const bf16x8*)(p0 + 8);
        bf16x8 a1 = *(const bf16x8*)p1, b1 = *(const bf16x8*)(p1 + 8);
        bf16x8 a2 = *(const bf16x8*)p2, b2 = *(const bf16x8*)(p2 + 8);
        bf16x8 a3 = *(const bf16x8*)p3, b3 = *(const bf16x8*)(p3 + 8);
#pragma unroll
        for (int j = 0; j < 8; ++j) {
            s[j]     += (float)a0[j] + (float)a1[j] + (float)a2[j] + (float)a3[j];
            s[8 + j] += (float)b0[j] + (float)b1[j] + (float)b2[j] + (float)b3[j];
        }
    }
    for (; e < e1; ++e) {
        const __bf16* pr = &hWb[(size_t)srcs[e] * F + lane * 16];
        bf16x8 v0 = *(const bf16x8*)pr;
        bf16x8 v1 = *(const bf16x8*)(pr + 8);
#pragma unroll
        for (int j = 0; j < 8; ++j) { s[j] += (float)v0[j]; s[8 + j] += (float)v1[j]; }
    }
    float p = 0.0f;
#pragma unroll
    for (int q = 0; q < 4; ++q) {
        float4 bb = *(const float4*)&bias[lane * 16 + q * 4];
        float4 ww = *(const float4*)&w2l[lane * 16 + q * 4];
        p += fmaxf(fmaf(di, s[q * 4 + 0], bb.x), 0.0f) * ww.x;
        p += fmaxf(fmaf(di, s[q * 4 + 1], bb.y), 0.0f) * ww.y;
        p += fmaxf(fmaf(di, s[q * 4 + 2], bb.z), 0.0f) * ww.z;
        p += fmaxf(fmaf(di, s[q * 4 + 3], bb.w), 0.0f) * ww.w;
    }
#pragma unroll
    for (int d = 1; d < 8; d <<= 1) p += __shfl_xor(p, d);
    if (lane == 0) zt[node] = di * p;
}

// ---------------- layer-2 aggregation + pool: degree-sorted thread-per-node + atomics ------
__global__ __launch_bounds__(256) void k_pool(const float* __restrict__ zt, const float* __restrict__ dis,
                                              const int* __restrict__ rowptr, const int* __restrict__ srcs,
                                              const int* __restrict__ perm, const int* __restrict__ batch,
                                              float* __restrict__ gacc, int N) {
    int idx = blockIdx.x * 256 + threadIdx.x;
    if (idx >= N) return;
    int n = perm[idx];                    // wave-uniform degree -> no divergence waste
    float s = zt[n];
    int e0 = rowptr[n], e1 = rowptr[n + 1];
    int e = e0;
    for (; e + 4 <= e1; e += 4) {
        s += zt[srcs[e]] + zt[srcs[e + 1]] + zt[srcs[e + 2]] + zt[srcs[e + 3]];
    }
    for (; e < e1; ++e) s += zt[srcs[e]];
    unsafeAtomicAdd(&gacc[batch[n]], dis[n] * s);
}

__global__ __launch_bounds__(256) void k_final(const float* __restrict__ gacc, const int* __restrict__ gstart,
                                               const float* __restrict__ cconst, const float* __restrict__ blin,
                                               float* __restrict__ out, int G) {
    int g = blockIdx.x * 256 + threadIdx.x;
    if (g < G) {
        int c = gstart[g + 1] - gstart[g];
        out[g] = (c > 0) ? (gacc[g] / (float)c + cconst[0]) : blin[0];
    }
}

// ---------------- launch ----------------

extern "C" void kernel_launch(void* const* d_in, const int* in_sizes, int n_in,
                              void* d_out, int out_size, void* d_ws, size_t ws_size,
                              hipStream_t stream) {
    const float* x    = (const float*)d_in[0];
    const int*   ei   = (const int*)d_in[1];
    const int*   batch= (const int*)d_in[2];
    const float* W1   = (const float*)d_in[3];
    const float* b1   = (const float*)d_in[4];
    const float* W2   = (const float*)d_in[5];
    const float* b2   = (const float*)d_in[6];
    const float* Wlin = (const float*)d_in[7];
    const float* blin = (const float*)d_in[8];
    float* out = (float*)d_out;

    const int N = in_sizes[2];          // 100000
    const int E = in_sizes[1] / 2;      // 600000
    const int G = out_size;             // 512
    const int* src = ei;
    const int* dst = ei + E;

    char* p = (char*)d_ws;
    auto take = [&](size_t bytes) { char* q = p; p += (bytes + 255) & ~(size_t)255; return q; };
    __bf16* hWb    = (__bf16*)take((size_t)N * F * 2);  // bf16( dis * (x @ W1) )
    float*  ztbuf  = (float*)take((size_t)N * 4);
    float*  deg    = (float*)take((size_t)N * 4);
    float*  dis    = (float*)take((size_t)N * 4);
    int*    rowptr = (int*)  take((size_t)(N + 1) * 4);
    int*    cursor = (int*)  take((size_t)N * 4);
    int*    srcs   = (int*)  take((size_t)E * 4);
    int*    perm   = (int*)  take((size_t)N * 4);
    int*    bsum   = (int*)  take(4096);
    int*    histg  = (int*)  take(64 * 4);
    int*    bcur   = (int*)  take(64 * 4);
    int*    gstart = (int*)  take((size_t)(G + 1) * 4);
    float*  gacc   = (float*)take((size_t)G * 4);
    float*  w2l    = (float*)take((size_t)F * 4);
    float*  cconst = (float*)take(256);
    __bf16* Bswz   = (__bf16*)take((size_t)F * F * 2);

    const int nbN  = (N + 255) / 256;
    const int nbE4 = (E + 1023) / 1024;     // 4 edges/thread
    const int nbS  = (N + 1023) / 1024;
    const int bG   = (G + 255) / 256;

    k_prep <<<65 + bG + nbN, 256, 0, stream>>>(W1, W2, Wlin, b2, blin, batch,
                                               Bswz, w2l, cconst, gstart, histg, deg, gacc, N, G, bG);
    k_count<<<nbE4, 256, 0, stream>>>(dst, deg, E);
    k_scan1<<<nbS, 256, 0, stream>>>(deg, rowptr, bsum, dis, histg, N);
    k_scan3<<<nbN, 256, 0, stream>>>(rowptr, bsum, cursor, histg, bcur, N, E);
    k_fill <<<nbN + nbE4, 256, 0, stream>>>(src, dst, deg, cursor, srcs, bcur, perm, E, N, nbN);

    k_gemm_mfma<<<(N + 127) / 128, 256, 0, stream>>>(x, Bswz, dis, hWb, N);
    k_agg_z<<<(N + 31) / 32, 256, 0, stream>>>(hWb, dis, rowptr, srcs, perm, b1, w2l, ztbuf, N);
    k_pool <<<nbN, 256, 0, stream>>>(ztbuf, dis, rowptr, srcs, perm, batch, gacc, N);
    k_final<<<bG, 256, 0, stream>>>(gacc, gstart, cconst, blin, out, G);
}

// Round 13
// 221.423 us; speedup vs baseline: 2.6310x; 1.3214x over previous
//
#include <hip/hip_runtime.h>

#define F 128

typedef __bf16 bf16x8 __attribute__((ext_vector_type(8)));
typedef float f32x4 __attribute__((ext_vector_type(4)));

// ---------------- fused prep ----------------
// blocks 0..63: W1 swizzle->bf16 fragments; block 64: w2l/cconst + zero histg;
// blocks 65..65+bG-1: gstart; rest: deg = 1 init.
__global__ __launch_bounds__(256) void k_prep(const float* __restrict__ W1, const float* __restrict__ W2,
                                              const float* __restrict__ Wlin, const float* __restrict__ b2,
                                              const float* __restrict__ blin, const int* __restrict__ batch,
                                              __bf16* __restrict__ Bswz, float* __restrict__ w2l,
                                              float* __restrict__ cconst, int* __restrict__ gstart,
                                              int* __restrict__ histg, float* __restrict__ deg,
                                              int N, int G, int bG) {
    int bid = blockIdx.x;
    int tid = threadIdx.x;
    if (bid < 64) {
        // Bswz[((t*8+c)*64+lane)*8+j] = W1[t*32+(lane>>4)*8+j][c*16+(lane&15)]
        int o = bid * 256 + tid;
        int j = o & 7, lane = (o >> 3) & 63, tc = o >> 9;
        int t = tc >> 3, c = tc & 7;
        int k = t * 32 + (lane >> 4) * 8 + j;
        int n = c * 16 + (lane & 15);
        Bswz[o] = (__bf16)W1[k * F + n];
    } else if (bid == 64) {
        __shared__ float sh[F];
        if (tid < F) {
            float s = 0.0f;
            for (int j = 0; j < F; j += 4) {
                float4 w = *(const float4*)&W2[tid * F + j];
                float4 l = *(const float4*)&Wlin[j];
                s += w.x * l.x + w.y * l.y + w.z * l.z + w.w * l.w;
            }
            w2l[tid] = s;
            sh[tid] = b2[tid] * Wlin[tid];
        } else if (tid < F + 64) {
            histg[tid - F] = 0;
        }
        __syncthreads();
        if (tid == 0) {
            float c = blin[0];
            for (int j = 0; j < F; ++j) c += sh[j];
            *cconst = c;
        }
    } else if (bid < 65 + bG) {
        int g = (bid - 65) * 256 + tid;
        if (g < G) {
            int lo = 0, hi = N;
            while (lo < hi) { int mid = (lo + hi) >> 1; if (batch[mid] < g) lo = mid + 1; else hi = mid; }
            gstart[g] = lo;
            if (g == 0) gstart[G] = N;
        }
    } else {
        int i = (bid - 65 - bG) * 256 + tid;
        if (i < N) deg[i] = 1.0f;           // self-loop
    }
}

// degree count: 4 edges/thread via int4, random-address atomics
__global__ __launch_bounds__(256) void k_count(const int* __restrict__ dst, float* deg, int E) {
    int base = (blockIdx.x * 256 + threadIdx.x) * 4;
    if (base + 4 <= E) {
        int4 d = *(const int4*)(dst + base);
        unsafeAtomicAdd(&deg[d.x], 1.0f);
        unsafeAtomicAdd(&deg[d.y], 1.0f);
        unsafeAtomicAdd(&deg[d.z], 1.0f);
        unsafeAtomicAdd(&deg[d.w], 1.0f);
    } else {
        for (int i = base; i < E; ++i) unsafeAtomicAdd(&deg[dst[i]], 1.0f);
    }
}

// exclusive scan of indeg (=deg-1), 1024 elems/block; dis = rsqrt(deg); + degree histogram
__global__ __launch_bounds__(256) void k_scan1(const float* __restrict__ deg, int* __restrict__ pref,
                                               int* __restrict__ bsum, float* __restrict__ dis,
                                               int* __restrict__ histg, int N) {
    int t = threadIdx.x;
    __shared__ int lh[64];
    __shared__ int wtot[4];
    if (t < 64) lh[t] = 0;
    int base = blockIdx.x * 1024 + t * 4;
    int v[4]; int s = 0;
#pragma unroll
    for (int j = 0; j < 4; ++j) {
        int idx = base + j;
        float dv = (idx < N) ? deg[idx] : 1.0f;
        if (idx < N) dis[idx] = rsqrtf(dv);
        v[j] = (idx < N) ? ((int)dv - 1) : 0; s += v[j];
    }
    int lane = t & 63, w = t >> 6;
    int inc = s;
#pragma unroll
    for (int d = 1; d < 64; d <<= 1) { int o = __shfl_up(inc, d); if (lane >= d) inc += o; }
    if (lane == 63) wtot[w] = inc;
    __syncthreads();                          // covers lh init + wtot
#pragma unroll
    for (int j = 0; j < 4; ++j)
        if (base + j < N) atomicAdd(&lh[min(v[j], 63)], 1);
    int woff = 0;
#pragma unroll
    for (int i = 0; i < 4; ++i) if (i < w) woff += wtot[i];
    int run = woff + inc - s;
#pragma unroll
    for (int j = 0; j < 4; ++j) { int idx = base + j; if (idx < N) pref[idx] = run; run += v[j]; }
    if (t == 255) bsum[blockIdx.x] = woff + inc;
    __syncthreads();
    if (t < 64 && lh[t] > 0) atomicAdd(&histg[t], lh[t]);
}

// add block offsets (reduce bsum[0..chunk) in-block); block 0 also scans the 64-bin histogram
__global__ __launch_bounds__(256) void k_scan3(int* __restrict__ pref, const int* __restrict__ bsum,
                                               int* __restrict__ cursor, const int* __restrict__ histg,
                                               int* __restrict__ bcur, int N, int E) {
    int t = threadIdx.x;
    int chunk = blockIdx.x >> 2;
    int partial = 0;
    for (int i = t; i < chunk; i += 256) partial += bsum[i];
    int lane = t & 63, w = t >> 6;
#pragma unroll
    for (int d = 1; d < 64; d <<= 1) partial += __shfl_xor(partial, d);
    __shared__ int ws4[4];
    if (lane == 0) ws4[w] = partial;
    __syncthreads();
    int off = ws4[0] + ws4[1] + ws4[2] + ws4[3];
    int i = blockIdx.x * 256 + t;
    if (i < N) {
        int v = pref[i] + off;
        pref[i] = v;
        cursor[i] = v;
    }
    if (i == 0) pref[N] = E;
    if (blockIdx.x == 0 && t < 64) {          // exclusive scan of degree histogram -> bucket cursors
        int h = histg[t];
        int inc2 = h;
#pragma unroll
        for (int d = 1; d < 64; d <<= 1) { int o = __shfl_up(inc2, d); if (t >= d) inc2 += o; }
        bcur[t] = inc2 - h;
    }
}

// CSR fill (edge-parallel blocks, 4 edges/thread) + degree-sorted perm scatter (node blocks)
__global__ __launch_bounds__(256) void k_fill(const int* __restrict__ src, const int* __restrict__ dst,
                                              const float* __restrict__ deg, int* __restrict__ cursor,
                                              int* __restrict__ srcs, int* __restrict__ bcur,
                                              int* __restrict__ perm, int E, int N, int nbN) {
    int bid = blockIdx.x, tid = threadIdx.x;
    if (bid < nbN) {
        __shared__ int lcnt[64], lbase[64];
        if (tid < 64) lcnt[tid] = 0;
        __syncthreads();
        int n = bid * 256 + tid;
        int b = 0, r = 0;
        if (n < N) {
            b = min((int)deg[n] - 1, 63);
            r = atomicAdd(&lcnt[b], 1);
        }
        __syncthreads();
        if (tid < 64 && lcnt[tid] > 0) lbase[tid] = atomicAdd(&bcur[tid], lcnt[tid]);
        __syncthreads();
        if (n < N) perm[lbase[b] + r] = n;
    } else {
        int base = ((bid - nbN) * 256 + tid) * 4;
        if (base + 4 <= E) {
            int4 s4 = *(const int4*)(src + base);
            int4 d4 = *(const int4*)(dst + base);
            srcs[atomicAdd(&cursor[d4.x], 1)] = s4.x;
            srcs[atomicAdd(&cursor[d4.y], 1)] = s4.y;
            srcs[atomicAdd(&cursor[d4.z], 1)] = s4.z;
            srcs[atomicAdd(&cursor[d4.w], 1)] = s4.w;
        } else {
            for (int e = base; e < E; ++e) {
                srcs[atomicAdd(&cursor[dst[e]], 1)] = src[e];
            }
        }
    }
}

// ---------------- MFMA GEMM: Yb[n] = bf16( dis[n] * (X @ W)[n] ) ----------------
// R8 form: 1-deep A prefetch, batched coalesced B loads (L2-resident), t-loop not unrolled.
__global__ __launch_bounds__(256) void k_gemm_mfma(const float* __restrict__ X,
                                                   const __bf16* __restrict__ Bswz,
                                                   const float* __restrict__ dis,
                                                   __bf16* __restrict__ Yb, int N) {
    int lane = threadIdx.x & 63, wave = threadIdx.x >> 6;
    int quad = lane >> 4, m = lane & 15;
    int r0 = blockIdx.x * 128 + wave * 32;

    f32x4 acc[2][8];
#pragma unroll
    for (int rt = 0; rt < 2; ++rt)
#pragma unroll
        for (int c = 0; c < 8; ++c) acc[rt][c] = (f32x4)0.0f;

    int ra = r0 + m;      if (ra >= N) ra = N - 1;
    int rb = r0 + 16 + m; if (rb >= N) rb = N - 1;
    const float* pxa = &X[(size_t)ra * F + quad * 8];
    const float* pxb = &X[(size_t)rb * F + quad * 8];

    float4 a0 = *(const float4*)pxa, a1 = *(const float4*)(pxa + 4);
    float4 a2 = *(const float4*)pxb, a3 = *(const float4*)(pxb + 4);

#pragma unroll 1
    for (int t = 0; t < 4; ++t) {
        const __bf16* bp = Bswz + (size_t)t * 4096 + lane * 8;
        bf16x8 B[8];
#pragma unroll
        for (int c = 0; c < 8; ++c) B[c] = *(const bf16x8*)(bp + c * 512);

        float fa[8] = {a0.x, a0.y, a0.z, a0.w, a1.x, a1.y, a1.z, a1.w};
        float fb[8] = {a2.x, a2.y, a2.z, a2.w, a3.x, a3.y, a3.z, a3.w};
        bf16x8 ah0, al0, ah1, al1;
#pragma unroll
        for (int j = 0; j < 8; ++j) {
            __bf16 h0 = (__bf16)fa[j]; ah0[j] = h0; al0[j] = (__bf16)(fa[j] - (float)h0);
            __bf16 h1 = (__bf16)fb[j]; ah1[j] = h1; al1[j] = (__bf16)(fb[j] - (float)h1);
        }
        if (t < 3) {
            a0 = *(const float4*)(pxa + (t + 1) * 32);
            a1 = *(const float4*)(pxa + (t + 1) * 32 + 4);
            a2 = *(const float4*)(pxb + (t + 1) * 32);
            a3 = *(const float4*)(pxb + (t + 1) * 32 + 4);
        }
#pragma unroll
        for (int c = 0; c < 8; ++c) {
            acc[0][c] = __builtin_amdgcn_mfma_f32_16x16x32_bf16(ah0, B[c], acc[0][c], 0, 0, 0);
            acc[0][c] = __builtin_amdgcn_mfma_f32_16x16x32_bf16(al0, B[c], acc[0][c], 0, 0, 0);
            acc[1][c] = __builtin_amdgcn_mfma_f32_16x16x32_bf16(ah1, B[c], acc[1][c], 0, 0, 0);
            acc[1][c] = __builtin_amdgcn_mfma_f32_16x16x32_bf16(al1, B[c], acc[1][c], 0, 0, 0);
        }
    }

#pragma unroll
    for (int rt = 0; rt < 2; ++rt) {
        int rbase = r0 + rt * 16 + quad * 4;
#pragma unroll
        for (int r = 0; r < 4; ++r) {
            int row = rbase + r;
            if (row < N) {
                float dr = dis[row];
#pragma unroll
                for (int c = 0; c < 8; ++c)
                    Yb[(size_t)row * F + c * 16 + m] = (__bf16)(acc[rt][c][r] * dr);
            }
        }
    }
}

// ---------------- layer-1 aggregation + zt = dis*(relu(b1+dis*sum).w2l), degree-sorted ------
// R8 form: 8 lanes/node, 4-edge unroll (8 loads/lane in flight), degree-sorted perm.
__global__ __launch_bounds__(256) void k_agg_z(const __bf16* __restrict__ hWb, const float* __restrict__ dis,
                                               const int* __restrict__ rowptr, const int* __restrict__ srcs,
                                               const int* __restrict__ perm,
                                               const float* __restrict__ bias, const float* __restrict__ w2l,
                                               float* __restrict__ zt, int N) {
    int idx = blockIdx.x * 32 + (threadIdx.x >> 3);
    if (idx >= N) return;
    int node = perm[idx];
    int lane = threadIdx.x & 7;                   // 8 lanes/node, 16 elems/lane
    float di = dis[node];
    float s[16];
    {
        const __bf16* pr = &hWb[(size_t)node * F + lane * 16];
        bf16x8 v0 = *(const bf16x8*)pr;
        bf16x8 v1 = *(const bf16x8*)(pr + 8);
#pragma unroll
        for (int j = 0; j < 8; ++j) { s[j] = (float)v0[j]; s[8 + j] = (float)v1[j]; }
    }
    int e0 = rowptr[node], e1 = rowptr[node + 1];
    int e = e0;
    for (; e + 4 <= e1; e += 4) {
        int i0 = srcs[e], i1 = srcs[e + 1], i2 = srcs[e + 2], i3 = srcs[e + 3];
        const __bf16* p0 = &hWb[(size_t)i0 * F + lane * 16];
        const __bf16* p1 = &hWb[(size_t)i1 * F + lane * 16];
        const __bf16* p2 = &hWb[(size_t)i2 * F + lane * 16];
        const __bf16* p3 = &hWb[(size_t)i3 * F + lane * 16];
        bf16x8 a0 = *(const bf16x8*)p0, b0 = *(const bf16x8*)(p0 + 8);
        bf16x8 a1 = *(const bf16x8*)p1, b1 = *(const bf16x8*)(p1 + 8);
        bf16x8 a2 = *(const bf16x8*)p2, b2 = *(const bf16x8*)(p2 + 8);
        bf16x8 a3 = *(const bf16x8*)p3, b3 = *(const bf16x8*)(p3 + 8);
#pragma unroll
        for (int j = 0; j < 8; ++j) {
            s[j]     += (float)a0[j] + (float)a1[j] + (float)a2[j] + (float)a3[j];
            s[8 + j] += (float)b0[j] + (float)b1[j] + (float)b2[j] + (float)b3[j];
        }
    }
    for (; e < e1; ++e) {
        const __bf16* pr = &hWb[(size_t)srcs[e] * F + lane * 16];
        bf16x8 v0 = *(const bf16x8*)pr;
        bf16x8 v1 = *(const bf16x8*)(pr + 8);
#pragma unroll
        for (int j = 0; j < 8; ++j) { s[j] += (float)v0[j]; s[8 + j] += (float)v1[j]; }
    }
    float p = 0.0f;
#pragma unroll
    for (int q = 0; q < 4; ++q) {
        float4 bb = *(const float4*)&bias[lane * 16 + q * 4];
        float4 ww = *(const float4*)&w2l[lane * 16 + q * 4];
        p += fmaxf(fmaf(di, s[q * 4 + 0], bb.x), 0.0f) * ww.x;
        p += fmaxf(fmaf(di, s[q * 4 + 1], bb.y), 0.0f) * ww.y;
        p += fmaxf(fmaf(di, s[q * 4 + 2], bb.z), 0.0f) * ww.z;
        p += fmaxf(fmaf(di, s[q * 4 + 3], bb.w), 0.0f) * ww.w;
    }
#pragma unroll
    for (int d = 1; d < 8; d <<= 1) p += __shfl_xor(p, d);
    if (lane == 0) zt[node] = di * p;
}

// ---------------- layer-2 aggregation + mean-pool: one block per graph, no atomics ----------
// Natural node order: adjacent threads read adjacent CSR ranges (index stream coalesces).
__global__ __launch_bounds__(256) void k_pool(const float* __restrict__ zt, const float* __restrict__ dis,
                                              const int* __restrict__ rowptr, const int* __restrict__ srcs,
                                              const int* __restrict__ gstart, const float* __restrict__ cconst,
                                              const float* __restrict__ blin, float* __restrict__ out, int G) {
    int g = blockIdx.x;
    int g0 = gstart[g], g1 = gstart[g + 1];
    float acc = 0.0f;
    for (int n = g0 + threadIdx.x; n < g1; n += 256) {
        float s = zt[n];
        int e0 = rowptr[n], e1 = rowptr[n + 1];
        int e = e0;
        for (; e + 4 <= e1; e += 4) {
            s += zt[srcs[e]] + zt[srcs[e + 1]] + zt[srcs[e + 2]] + zt[srcs[e + 3]];
        }
        for (; e < e1; ++e) s += zt[srcs[e]];
        acc += dis[n] * s;
    }
#pragma unroll
    for (int d = 1; d < 64; d <<= 1) acc += __shfl_xor(acc, d);
    __shared__ float ws4[4];
    if ((threadIdx.x & 63) == 0) ws4[threadIdx.x >> 6] = acc;
    __syncthreads();
    if (threadIdx.x == 0) {
        float sum = ws4[0] + ws4[1] + ws4[2] + ws4[3];
        int c = g1 - g0;
        out[g] = (c > 0) ? (sum / (float)c + cconst[0]) : blin[0];
    }
}

// ---------------- launch ----------------

extern "C" void kernel_launch(void* const* d_in, const int* in_sizes, int n_in,
                              void* d_out, int out_size, void* d_ws, size_t ws_size,
                              hipStream_t stream) {
    const float* x    = (const float*)d_in[0];
    const int*   ei   = (const int*)d_in[1];
    const int*   batch= (const int*)d_in[2];
    const float* W1   = (const float*)d_in[3];
    const float* b1   = (const float*)d_in[4];
    const float* W2   = (const float*)d_in[5];
    const float* b2   = (const float*)d_in[6];
    const float* Wlin = (const float*)d_in[7];
    const float* blin = (const float*)d_in[8];
    float* out = (float*)d_out;

    const int N = in_sizes[2];          // 100000
    const int E = in_sizes[1] / 2;      // 600000
    const int G = out_size;             // 512
    const int* src = ei;
    const int* dst = ei + E;

    char* p = (char*)d_ws;
    auto take = [&](size_t bytes) { char* q = p; p += (bytes + 255) & ~(size_t)255; return q; };
    __bf16* hWb    = (__bf16*)take((size_t)N * F * 2);  // bf16( dis * (x @ W1) )
    float*  ztbuf  = (float*)take((size_t)N * 4);
    float*  deg    = (float*)take((size_t)N * 4);
    float*  dis    = (float*)take((size_t)N * 4);
    int*    rowptr = (int*)  take((size_t)(N + 1) * 4);
    int*    cursor = (int*)  take((size_t)N * 4);
    int*    srcs   = (int*)  take((size_t)E * 4);
    int*    perm   = (int*)  take((size_t)N * 4);
    int*    bsum   = (int*)  take(4096);
    int*    histg  = (int*)  take(64 * 4);
    int*    bcur   = (int*)  take(64 * 4);
    int*    gstart = (int*)  take((size_t)(G + 1) * 4);
    float*  w2l    = (float*)take((size_t)F * 4);
    float*  cconst = (float*)take(256);
    __bf16* Bswz   = (__bf16*)take((size_t)F * F * 2);

    const int nbN  = (N + 255) / 256;
    const int nbE4 = (E + 1023) / 1024;     // 4 edges/thread
    const int nbS  = (N + 1023) / 1024;
    const int bG   = (G + 255) / 256;

    k_prep <<<65 + bG + nbN, 256, 0, stream>>>(W1, W2, Wlin, b2, blin, batch,
                                               Bswz, w2l, cconst, gstart, histg, deg, N, G, bG);
    k_count<<<nbE4, 256, 0, stream>>>(dst, deg, E);
    k_scan1<<<nbS, 256, 0, stream>>>(deg, rowptr, bsum, dis, histg, N);
    k_scan3<<<nbN, 256, 0, stream>>>(rowptr, bsum, cursor, histg, bcur, N, E);
    k_fill <<<nbN + nbE4, 256, 0, stream>>>(src, dst, deg, cursor, srcs, bcur, perm, E, N, nbN);

    k_gemm_mfma<<<(N + 127) / 128, 256, 0, stream>>>(x, Bswz, dis, hWb, N);
    k_agg_z<<<(N + 31) / 32, 256, 0, stream>>>(hWb, dis, rowptr, srcs, perm, b1, w2l, ztbuf, N);
    k_pool <<<G, 256, 0, stream>>>(ztbuf, dis, rowptr, srcs, gstart, cconst, blin, out, G);
}